// Round 5
// baseline (169.066 us; speedup 1.0000x reference)
//
#include <hip/hip_runtime.h>

// LengthRegulator: B=32, T=512, D=512, max_len=2048 (fixed by the problem).
// out[b, t, :] = x[b, searchsorted_right(cumsum(duration[b]), t), :] for
// t < sum(duration[b]), else zeros. mel_lengths[b] = max(sum, 1), stored as
// float at the tail of d_out (harness reads whole buffer as float32).
//
// Rounds 0-4 evidence: four structurally different copies (block-gather,
// table-gather, phoneme-scatter, contiguous slab-sweep; NT and plain stores)
// ALL ran at ~2 TB/s effective, while the harness poison fill sustains
// 6.5-6.8 TB/s. Address pattern and indirection are falsified as the cause.
// The never-tested variable is LAUNCH GEOMETRY: all our variants used max
// occupancy (8-32 waves/CU, >8k concurrent store streams); the fill runs at
// ~9% occupancy (~1k waves, few deep streams per DRAM channel). This round
// clones the fill's geometry:
//
//   A) lr_scan_kernel (32 blocks, proven in R1/R4): wave-shfl cumsum,
//      scatter frame->phoneme table idxt[b][t] into d_ws (-1 = padding).
//   B) lr_copy_kernel: 512 blocks x 256 threads (2 blocks/CU, 2 waves/SIMD),
//      grid-stride sweep over the flat f4 output space, 64 steps/thread,
//      8-deep unroll (8 independent idxt loads -> 8 x-loads -> 8 stores) so
//      each wave keeps 8 outstanding gathers in flight. Flat f4 element e:
//      idxt index = e>>7, batch = e>>18, lane = e&127. Plain stores.

#define BB      32
#define TT      512
#define DD      512
#define MAXLEN  2048
#define RPF     (DD / 4)               // 128 f4 per frame row
#define NF4     (BB * MAXLEN * RPF)    // 2^23 flat f4 elements
#define CBLK    512
#define CTH     (CBLK * 256)           // 131072 copy threads
#define STEPS   (NF4 / CTH)            // 64 grid-stride steps

typedef float f4 __attribute__((ext_vector_type(4)));

__global__ __launch_bounds__(512) void lr_scan_kernel(
    const int* __restrict__ dur, int* __restrict__ idxt,
    float* __restrict__ mel_out) {
  __shared__ int wsum[8];
  const int b    = blockIdx.x;
  const int tid  = threadIdx.x;
  const int lane = tid & 63;
  const int wid  = tid >> 6;

  const int d = dur[b * TT + tid];
  int v = d;
  // Inclusive scan within the 64-lane wave (6 shfl steps, no barriers).
#pragma unroll
  for (int off = 1; off < 64; off <<= 1) {
    int n = __shfl_up(v, off, 64);
    if (lane >= off) v += n;
  }
  if (lane == 63) wsum[wid] = v;
  __syncthreads();

  int woff = 0, dsum = 0;
#pragma unroll
  for (int i = 0; i < 8; ++i) {
    int w = wsum[i];
    dsum += w;
    if (i < wid) woff += w;
  }
  v += woff;  // inclusive cumsum at phoneme tid

  if (tid == 0) mel_out[b] = (float)(dsum > 1 ? dsum : 1);

  // Scatter: phoneme tid owns output frames [v - d, v), truncated at MAXLEN.
  int start = v - d;
  int end   = v;
  if (start > MAXLEN) start = MAXLEN;
  if (end   > MAXLEN) end   = MAXLEN;
  int* row = idxt + b * MAXLEN;
  for (int t = start; t < end; ++t) row[t] = tid;
  // Padding tail [dsum, MAXLEN): coalesced -1 fill.
  for (int t = dsum + tid; t < MAXLEN; t += TT) row[t] = -1;
}

__global__ __launch_bounds__(256) void lr_copy_kernel(
    const int* __restrict__ idxt, const f4* __restrict__ x,
    f4* __restrict__ out) {
  const int g = blockIdx.x * 256 + threadIdx.x;
  const f4 zero = {0.f, 0.f, 0.f, 0.f};

  for (int s = 0; s < STEPS; s += 8) {
    // Phase 1: 8 independent frame-index loads (wave-uniform, L2-hot).
    int idx[8];
#pragma unroll
    for (int u = 0; u < 8; ++u) {
      const size_t e = (size_t)g + (size_t)(s + u) * CTH;
      idx[u] = idxt[e >> 7];
    }
    // Phase 2: 8 independent gathers from x (1 KiB contiguous per wave).
    f4 v[8];
#pragma unroll
    for (int u = 0; u < 8; ++u) {
      const size_t e = (size_t)g + (size_t)(s + u) * CTH;
      v[u] = zero;
      if (idx[u] >= 0) {
        const size_t b = e >> 18;
        v[u] = x[(b * TT + (size_t)idx[u]) * RPF + (e & (RPF - 1))];
      }
    }
    // Phase 3: 8 plain streaming stores (fill mode).
#pragma unroll
    for (int u = 0; u < 8; ++u) {
      const size_t e = (size_t)g + (size_t)(s + u) * CTH;
      out[e] = v[u];
    }
  }
}

extern "C" void kernel_launch(void* const* d_in, const int* in_sizes, int n_in,
                              void* d_out, int out_size, void* d_ws, size_t ws_size,
                              hipStream_t stream) {
  const float* x   = (const float*)d_in[0];
  const int*   dur = (const int*)d_in[1];
  // d_in[2] is max_len (=2048), static; hard-coded.
  float* out = (float*)d_out;
  float* mel_out = out + (size_t)BB * MAXLEN * DD;  // tail: 32 floats
  int* idxt = (int*)d_ws;                           // 32*2048*4 = 256 KiB

  lr_scan_kernel<<<BB, 512, 0, stream>>>(dur, idxt, mel_out);
  lr_copy_kernel<<<CBLK, 256, 0, stream>>>(idxt, (const f4*)x, (f4*)out);
}